// Round 10
// baseline (4166.095 us; speedup 1.0000x reference)
//
#include <hip/hip_runtime.h>
#include <hip/hip_fp16.h>

#define S 31
#define D 14
#define H 50
#define NB 16384
#define NITER 48
#define LAMR 1e-4f
#define TSC 2.8853900817779268f   // 2*log2(e), folded into W at prep

// ws float-index layout
#define WS_D2   0      // 48: global sum ||F-X||^2 per iter
#define WS_F2   64     // 48: global sum ||F||^2 per iter
#define WS_WC1  128    // [64 n][32 k] f16 (1024 dw): rows n=h: [Wh|Wx|bhx|0]*TSC
#define WS_WOC  1152   // [16 d][64 k] f16 (512 dw): k<50 Wo*TSC, k50 bo*TSC, else 0
#define WS_WF   1664   // [32 s][16 d] f16 (256 dw), unscaled
#define WS_OUTK 4096   // 48*NB floats

typedef _Float16 f16x2 __attribute__((ext_vector_type(2)));
typedef _Float16 f16x8 __attribute__((ext_vector_type(8)));
typedef float    f32x4 __attribute__((ext_vector_type(4)));

#if defined(__has_builtin) && __has_builtin(__builtin_amdgcn_rcpf)
#define FRCP(x) __builtin_amdgcn_rcpf(x)
#else
#define FRCP(x) (1.0f/(x))
#endif

#if defined(__has_builtin) && __has_builtin(__builtin_amdgcn_exp2f)
#define FEXP2(x) __builtin_amdgcn_exp2f(x)
#else
#define FEXP2(x) exp2f(x)
#endif

#define FDOT2(a,b,c) __builtin_amdgcn_fdot2((a),(b),(c),false)

__device__ __forceinline__ f16x2 pkrtz(float a, float b){
  auto r = __builtin_amdgcn_cvt_pkrtz(a, b);
  return __builtin_bit_cast(f16x2, r);
}

template<int CTRL>
__device__ __forceinline__ float dppadd(float v){
  int pv = __builtin_amdgcn_update_dpp(0, __builtin_bit_cast(int, v),
                                       CTRL, 0xF, 0xF, true);
  return v + __builtin_bit_cast(float, pv);
}

// triangular index, i<=j, 6x6
#define AIJ(i,j) ((i)*6 - ((i)*((i)+1))/2 + (j))

__device__ __forceinline__ float tfast(float x){
  // weights pre-scaled by 2*log2e: tanh(pre) = 1 - 2/(exp2(x)+1)
  float e = FEXP2(x);
  return 1.f - 2.f * FRCP(e + 1.f);
}

__global__ void prep_kernel(const float* __restrict__ Wh, const float* __restrict__ bh,
                            const float* __restrict__ Wx, const float* __restrict__ bx,
                            const float* __restrict__ Wo, const float* __restrict__ bo,
                            const float* __restrict__ Wf, float* __restrict__ ws){
  int t = threadIdx.x;                       // 1 block x 256
  for (int i=t;i<128;i+=256) ws[i]=0.f;      // zero norm accumulators
  // Wcomb1: B of L1, rows n=h (0..63), k-major: [Wh(0..13)|Wx(14..27)|bhx(28)|0]
  __half2* wc1 = (__half2*)(ws + WS_WC1);
  for (int i=t;i<1024;i+=256){
    int n=i>>4, kp=i&15, k0=2*kp, k1=2*kp+1;
    float v0=0.f, v1=0.f;
    if (n<H){
      v0 = (k0<14)? Wh[n*D+k0]*TSC : (k0<28)? Wx[n*D+(k0-14)]*TSC : (k0==28)? (bh[n]+bx[n])*TSC : 0.f;
      v1 = (k1<14)? Wh[n*D+k1]*TSC : (k1<28)? Wx[n*D+(k1-14)]*TSC : (k1==28)? (bh[n]+bx[n])*TSC : 0.f;
    }
    wc1[i] = __floats2half2_rn(v0,v1);
  }
  // WoCmb: A of L2, rows m=d (0..15), k-major over h: Wo (k<50), bo at k=50
  __half2* woc = (__half2*)(ws + WS_WOC);
  for (int i=t;i<512;i+=256){
    int d=i>>5, kp=i&31, k0=2*kp, k1=2*kp+1;
    float v0=0.f, v1=0.f;
    if (d<D){
      v0 = (k0<H)? Wo[d*H+k0]*TSC : (k0==H)? bo[d]*TSC : 0.f;
      v1 = (k1<H)? Wo[d*H+k1]*TSC : (k1==H)? bo[d]*TSC : 0.f;
    }
    woc[i] = __floats2half2_rn(v0,v1);
  }
  __half2* wf = (__half2*)(ws + WS_WF);      // [32 s][16 d]
  for (int i=t;i<256;i+=256){
    int s=i>>3, dp=i&7, d0=2*dp, d1=2*dp+1;
    float v0=(s<S&&d0<D)?Wf[s*D+d0]:0.f, v1=(s<S&&d1<D)?Wf[s*D+d1]:0.f;
    wf[i] = __floats2half2_rn(v0,v1);
  }
}

// One wave per block. 2 elems/wave: rows 0-31 = elem A, 32-63 = elem B.
// A/B frags loaded with matching k-maps (k-permutation cancels in mfma).
__global__ __launch_bounds__(64, 3)
void solver_kernel(const float* __restrict__ x,
                   const f16x8* __restrict__ wc1, const f16x8* __restrict__ woc,
                   const f16x2* __restrict__ wf,
                   float* __restrict__ outk, float* __restrict__ d2p, float* __restrict__ f2p){
  const int l = threadIdx.x;
  const int a = l & 15;
  const int g = l >> 4;
  const int elemA = blockIdx.x*2;

  __shared__ __align__(16) unsigned char AZ[4096];   // [64 r][64B]: k f16: x|z|1|pad
  __shared__ __align__(16) unsigned char HB[8192];   // [64 r][128B] ^ ((r&7)<<4)

  // prologue: zero AZ row l, stage x (k 0..13) and 1.0 (k=28)
#pragma unroll
  for (int i=0;i<16;++i) *(float*)(AZ + l*64 + i*4) = 0.f;
  {
    int s = l & 31, e = l >> 5;
    if (s < S){
      const float* xr = x + ((size_t)(elemA+e)*S + s)*D;
#pragma unroll
      for (int i=0;i<7;++i){
        __half2 h2 = __floats2half2_rn(xr[2*i], xr[2*i+1]);
        *(f16x2*)(AZ + l*64 + i*4) = __builtin_bit_cast(f16x2, h2);
      }
    }
    *(_Float16*)(AZ + l*64 + 56) = (_Float16)1.0f;   // k=28 bias column
  }
  // per-lane Wf frags: rows r=nt*16+a -> s=(nt&1)*16+a; dims g*4..g*4+3
  const f16x2 wfr0 = wf[a*8+g*2],      wfr1 = wf[a*8+g*2+1];
  const f16x2 wfr2 = wf[(16+a)*8+g*2], wfr3 = wf[(16+a)*8+g*2+1];

  const f16x2 zz = {(_Float16)0.f,(_Float16)0.f};
  const int zo0 = 28 + g*8;                      // z bytes (d-pair g*4)
  const int zo1 = (g==3) ? 60 : 32 + g*8;        // g=3 2nd pair = pad dims -> dump @60

  // history: [6 slots][8 = nt*2+w] f16x2 ; lane owns rows nt*16+a, dims g*4+0..3
  f16x2 Fh[48], Gh[48], fo[8];
  float GG[21];
#pragma unroll
  for (int i=0;i<48;++i){ Fh[i]=zz; Gh[i]=zz; }
#pragma unroll
  for (int i=0;i<21;++i) GG[i]=0.f;

#pragma unroll 1
  for (int kk=0; kk<50; ++kk){
    if (kk >= 2){
      float A_[21], yv[6];
      if (kk >= 6){
#pragma unroll
        for (int i=0;i<6;++i)
#pragma unroll
          for (int j=i;j<6;++j) A_[AIJ(i,j)] = GG[AIJ(i,j)] + ((i==j)?LAMR:0.f);
      } else {
        int lo = 6-kk;
#pragma unroll
        for (int i=0;i<6;++i)
#pragma unroll
          for (int j=i;j<6;++j){
            float v = GG[AIJ(i,j)] + ((i==j)?LAMR:0.f);
            A_[AIJ(i,j)] = (i>=lo)? v : ((i==j)?1e30f:0.f);
          }
      }
#pragma unroll
      for (int i=0;i<6;++i) yv[i]=1.f;
#pragma unroll
      for (int p=0;p<6;++p){
        float ip = FRCP(A_[AIJ(p,p)]);
        A_[AIJ(p,p)] = ip;
#pragma unroll
        for (int i=p+1;i<6;++i){
          float m = A_[AIJ(p,i)]*ip;
#pragma unroll
          for (int j=i;j<6;++j) A_[AIJ(i,j)] -= m*A_[AIJ(p,j)];
          yv[i] -= m*yv[p];
        }
      }
#pragma unroll
      for (int p=5;p>=0;--p){
        float acc=yv[p];
#pragma unroll
        for (int j=p+1;j<6;++j) acc -= A_[AIJ(p,j)]*yv[j];
        yv[p]=acc*A_[AIJ(p,p)];
      }
      float isum = FRCP(yv[0]+yv[1]+yv[2]+yv[3]+yv[4]+yv[5]);
      // Xk = sum_j alpha_j F_j ; alphas per elem (half-wave solves), exchanged
      f16x2 xk[8];
#pragma unroll
      for (int i=0;i<8;++i) xk[i]=zz;
#pragma unroll
      for (int j=0;j<6;++j){
        float ao = yv[j]*isum;
        float ot = __shfl_xor(ao, 32);
        float vA = (l<32)? ao : ot;
        float vB = (l<32)? ot : ao;
        _Float16 hA=(_Float16)vA, hB=(_Float16)vB;
        f16x2 a2A={hA,hA}, a2B={hB,hB};
#pragma unroll
        for (int i=0;i<4;++i) xk[i] += a2A*Fh[j*8+i];
#pragma unroll
        for (int i=4;i<8;++i) xk[i] += a2B*Fh[j*8+i];
      }
#pragma unroll
      for (int nt=0;nt<4;++nt){
        int r = nt*16 + a;
        *(f16x2*)(AZ + r*64 + zo0) = xk[nt*2];
        *(f16x2*)(AZ + r*64 + zo1) = xk[nt*2+1];
      }
    } else if (kk == 1){
      // X1 = F0
#pragma unroll
      for (int nt=0;nt<4;++nt){
        int r = nt*16 + a;
        *(f16x2*)(AZ + r*64 + zo0) = fo[nt*2];
        *(f16x2*)(AZ + r*64 + zo1) = fo[nt*2+1];
      }
    }
    // ---- L1: H = tanh([x|z|1]·Wc1), written to swizzled HB
#pragma unroll
    for (int nt=0;nt<4;++nt){
      f16x8 B = wc1[(nt*16+a)*4 + g];
#pragma unroll
      for (int mt=0;mt<4;++mt){
        f16x8 A = *(const f16x8*)(AZ + (mt*16+a)*64 + g*16);
        f32x4 c = {0.f,0.f,0.f,0.f};
        c = __builtin_amdgcn_mfma_f32_16x16x32_f16(A, B, c, 0,0,0);
#pragma unroll
        for (int q=0;q<4;++q){
          int r = mt*16 + g*4 + q;            // C: row=(l>>4)*4+q, col=a
          _Float16 hv = (_Float16)tfast(c[q]);
          if (nt==3 && a==2) hv = (_Float16)1.0f;   // h==50: constant-1 (bo) col
          *(_Float16*)(HB + ((r*128 + (nt*16+a)*2) ^ ((r&7)<<4))) = hv;
        }
      }
    }
    // ---- L2: F = tanh(Wo·H^T) ; lane gets F[d=g*4+q][r=nt*16+a]
    {
      f16x8 wA0 = woc[a*8 + g], wA1 = woc[a*8 + 4 + g];
#pragma unroll
      for (int nt=0;nt<4;++nt){
        int r2 = nt*16 + a;
        f16x8 b0 = *(const f16x8*)(HB + ((r2*128 +  0 + g*16) ^ ((r2&7)<<4)));
        f16x8 b1 = *(const f16x8*)(HB + ((r2*128 + 64 + g*16) ^ ((r2&7)<<4)));
        f32x4 c = {0.f,0.f,0.f,0.f};
        c = __builtin_amdgcn_mfma_f32_16x16x32_f16(wA0, b0, c, 0,0,0);
        c = __builtin_amdgcn_mfma_f32_16x16x32_f16(wA1, b1, c, 0,0,0);
        fo[nt*2]   = pkrtz(tfast(c[0]), tfast(c[1]));
        fo[nt*2+1] = pkrtz(tfast(c[2]), tfast(c[3]));
      }
    }
    // ---- g = F - X (X read back from AZ staging; pads are zero by construction)
    f16x2 go[8];
#pragma unroll
    for (int nt=0;nt<4;++nt){
      int r = nt*16 + a;
      f16x2 x0 = *(const f16x2*)(AZ + r*64 + zo0);
      f16x2 x1 = *(const f16x2*)(AZ + r*64 + zo1);
      go[nt*2]   = fo[nt*2]   - x0;
      go[nt*2+1] = fo[nt*2+1] - x1;
    }
    if (a == 15){  // s==31 rows (nt odd) are inactive
      fo[2]=zz; fo[3]=zz; fo[6]=zz; fo[7]=zz;
      go[2]=zz; go[3]=zz; go[6]=zz; go[7]=zz;
    }
    // ---- push: shift FIRST (f/g die at slot-5 write), then dots from history
#pragma unroll
    for (int j=0;j<5;++j)
#pragma unroll
      for (int i=0;i<8;++i){ Fh[j*8+i]=Fh[(j+1)*8+i]; Gh[j*8+i]=Gh[(j+1)*8+i]; }
#pragma unroll
    for (int i=0;i<8;++i){ Fh[40+i]=fo[i]; Gh[40+i]=go[i]; }
    float rv[16];   // [0..7]=elem A {dn0..4,d2,f2,po}, [8..15]=elem B
#pragma unroll
    for (int j=0;j<5;++j){
      float pa=0.f, pb=0.f;
#pragma unroll
      for (int i=0;i<4;++i) pa = FDOT2(Gh[40+i], Gh[j*8+i], pa);
#pragma unroll
      for (int i=4;i<8;++i) pb = FDOT2(Gh[40+i], Gh[j*8+i], pb);
      rv[j]=pa; rv[8+j]=pb;
    }
    {
      float pa=0.f,pb=0.f,qa=0.f,qb=0.f,ra=0.f,rb=0.f;
#pragma unroll
      for (int i=0;i<4;++i){
        pa = FDOT2(Gh[40+i], Gh[40+i], pa);
        qa = FDOT2(Fh[40+i], Fh[40+i], qa);
      }
#pragma unroll
      for (int i=4;i<8;++i){
        pb = FDOT2(Gh[40+i], Gh[40+i], pb);
        qb = FDOT2(Fh[40+i], Fh[40+i], qb);
      }
      ra = FDOT2(Fh[40+0], wfr0, ra); ra = FDOT2(Fh[40+1], wfr1, ra);
      ra = FDOT2(Fh[40+2], wfr2, ra); ra = FDOT2(Fh[40+3], wfr3, ra);
      rb = FDOT2(Fh[44+0], wfr0, rb); rb = FDOT2(Fh[44+1], wfr1, rb);
      rb = FDOT2(Fh[44+2], wfr2, rb); rb = FDOT2(Fh[44+3], wfr3, rb);
      rv[5]=pa; rv[13]=pb; rv[6]=qa; rv[14]=qb; rv[7]=ra; rv[15]=rb;
    }
#pragma unroll
    for (int i=0;i<16;++i) rv[i] = dppadd<0x121>(rv[i]);
#pragma unroll
    for (int i=0;i<16;++i) rv[i] = dppadd<0x122>(rv[i]);
#pragma unroll
    for (int i=0;i<16;++i) rv[i] = dppadd<0x124>(rv[i]);
#pragma unroll
    for (int i=0;i<16;++i) rv[i] = dppadd<0x128>(rv[i]);
#pragma unroll
    for (int i=0;i<16;++i) rv[i] += __shfl_xor(rv[i],16);
#pragma unroll
    for (int i=0;i<16;++i) rv[i] += __shfl_xor(rv[i],32);
    // GG update with own-elem values (lane<32 solves A, else B)
    const bool eB = (l >= 32);
#pragma unroll
    for (int i_=0;i_<5;++i_)
#pragma unroll
      for (int j_=i_;j_<5;++j_) GG[AIJ(i_,j_)] = GG[AIJ(i_+1,j_+1)];
#pragma unroll
    for (int j=0;j<5;++j) GG[AIJ(j,5)] = eB? rv[8+j] : rv[j];
    GG[AIJ(5,5)] = eB? rv[13] : rv[5];
    if (kk>=2 && l==0){
      atomicAdd(&d2p[kk-2], rv[5]+rv[13]);
      atomicAdd(&f2p[kk-2], rv[6]+rv[14]);
      outk[(size_t)(kk-2)*NB + elemA]     = rv[7];
      outk[(size_t)(kk-2)*NB + elemA + 1] = rv[15];
    }
  }
}

__global__ void final_kernel(const float* __restrict__ d2p, const float* __restrict__ f2p,
                             const float* __restrict__ outk, const float* __restrict__ bf,
                             float* __restrict__ out){
  int b = blockIdx.x*blockDim.x + threadIdx.x;
  float best = 1e8f; int kst = 0;
  for (int k=0;k<NITER;++k){
    float rel = sqrtf(d2p[k]) / (1e-5f + sqrtf(f2p[k]));
    if (rel < best){ best = rel; kst = k; }
  }
  out[b] = outk[(size_t)kst*NB + b] + bf[0];
}

extern "C" void kernel_launch(void* const* d_in, const int* in_sizes, int n_in,
                              void* d_out, int out_size, void* d_ws, size_t ws_size,
                              hipStream_t stream){
  const float* x  = (const float*)d_in[0];
  const float* Wh = (const float*)d_in[1];
  const float* bh = (const float*)d_in[2];
  const float* Wx = (const float*)d_in[3];
  const float* bx = (const float*)d_in[4];
  const float* Wo = (const float*)d_in[5];
  const float* bo = (const float*)d_in[6];
  const float* Wf = (const float*)d_in[7];
  const float* bf = (const float*)d_in[8];
  float* ws  = (float*)d_ws;
  float* out = (float*)d_out;

  hipLaunchKernelGGL(prep_kernel, dim3(1), dim3(256), 0, stream, Wh,bh,Wx,bx,Wo,bo,Wf,ws);
  hipLaunchKernelGGL(solver_kernel, dim3(NB/2), dim3(64), 0, stream,
                     x, (const f16x8*)(ws+WS_WC1), (const f16x8*)(ws+WS_WOC),
                     (const f16x2*)(ws+WS_WF),
                     ws+WS_OUTK, ws+WS_D2, ws+WS_F2);
  hipLaunchKernelGGL(final_kernel, dim3(NB/256), dim3(256), 0, stream,
                     ws+WS_D2, ws+WS_F2, ws+WS_OUTK, bf, out);
}

// Round 11
// 2909.136 us; speedup vs baseline: 1.4321x; 1.4321x over previous
//
#include <hip/hip_runtime.h>
#include <hip/hip_fp16.h>

#define S 31
#define D 14
#define H 50
#define NB 16384
#define NITER 48
#define LAMR 1e-4f
#define TSC 2.8853900817779268f   // 2*log2(e), folded into W at prep

// ws float-index layout
#define WS_D2   0      // 48: global sum ||F-X||^2 per iter
#define WS_F2   64     // 48: global sum ||F||^2 per iter
#define WS_WC1  128    // [64 n][32 k] f16 (1024 dw): rows n=h: [Wh|Wx|bhx|0]*TSC
#define WS_WOC  1152   // [16 d][64 k] f16 (512 dw): k<50 Wo*TSC, k50 bo*TSC, else 0
#define WS_WF   1664   // [32 s][16 d] f16 (256 dw), unscaled
#define WS_OUTK 4096   // 48*NB floats

typedef _Float16 f16x2 __attribute__((ext_vector_type(2)));
typedef _Float16 f16x4 __attribute__((ext_vector_type(4)));
typedef _Float16 f16x8 __attribute__((ext_vector_type(8)));
typedef float    f32x4 __attribute__((ext_vector_type(4)));

#if defined(__has_builtin) && __has_builtin(__builtin_amdgcn_rcpf)
#define FRCP(x) __builtin_amdgcn_rcpf(x)
#else
#define FRCP(x) (1.0f/(x))
#endif

#if defined(__has_builtin) && __has_builtin(__builtin_amdgcn_exp2f)
#define FEXP2(x) __builtin_amdgcn_exp2f(x)
#else
#define FEXP2(x) exp2f(x)
#endif

#define FDOT2(a,b,c) __builtin_amdgcn_fdot2((a),(b),(c),false)

__device__ __forceinline__ f16x2 pkrtz(float a, float b){
  auto r = __builtin_amdgcn_cvt_pkrtz(a, b);
  return __builtin_bit_cast(f16x2, r);
}

template<int CTRL>
__device__ __forceinline__ float dppadd(float v){
  int pv = __builtin_amdgcn_update_dpp(0, __builtin_bit_cast(int, v),
                                       CTRL, 0xF, 0xF, true);
  return v + __builtin_bit_cast(float, pv);
}

// triangular index, i<=j, 6x6
#define AIJ(i,j) ((i)*6 - ((i)*((i)+1))/2 + (j))

__device__ __forceinline__ float tfast(float x){
  // weights pre-scaled by 2*log2e: tanh(pre) = 1 - 2/(exp2(x)+1)
  float e = FEXP2(x);
  return 1.f - 2.f * FRCP(e + 1.f);
}

__global__ void prep_kernel(const float* __restrict__ Wh, const float* __restrict__ bh,
                            const float* __restrict__ Wx, const float* __restrict__ bx,
                            const float* __restrict__ Wo, const float* __restrict__ bo,
                            const float* __restrict__ Wf, float* __restrict__ ws){
  int t = threadIdx.x;                       // 1 block x 256
  for (int i=t;i<128;i+=256) ws[i]=0.f;      // zero norm accumulators
  // Wcomb1: rows n=h (0..63), k-major: [Wh(0..13)|Wx(14..27)|bhx(28)|0]
  __half2* wc1 = (__half2*)(ws + WS_WC1);
  for (int i=t;i<1024;i+=256){
    int n=i>>4, kp=i&15, k0=2*kp, k1=2*kp+1;
    float v0=0.f, v1=0.f;
    if (n<H){
      v0 = (k0<14)? Wh[n*D+k0]*TSC : (k0<28)? Wx[n*D+(k0-14)]*TSC : (k0==28)? (bh[n]+bx[n])*TSC : 0.f;
      v1 = (k1<14)? Wh[n*D+k1]*TSC : (k1<28)? Wx[n*D+(k1-14)]*TSC : (k1==28)? (bh[n]+bx[n])*TSC : 0.f;
    }
    wc1[i] = __floats2half2_rn(v0,v1);
  }
  // WoCmb: rows m=d (0..15), k-major over h: Wo (k<50), bo at k=50
  __half2* woc = (__half2*)(ws + WS_WOC);
  for (int i=t;i<512;i+=256){
    int d=i>>5, kp=i&31, k0=2*kp, k1=2*kp+1;
    float v0=0.f, v1=0.f;
    if (d<D){
      v0 = (k0<H)? Wo[d*H+k0]*TSC : (k0==H)? bo[d]*TSC : 0.f;
      v1 = (k1<H)? Wo[d*H+k1]*TSC : (k1==H)? bo[d]*TSC : 0.f;
    }
    woc[i] = __floats2half2_rn(v0,v1);
  }
  __half2* wf = (__half2*)(ws + WS_WF);      // [32 s][16 d]
  for (int i=t;i<256;i+=256){
    int s=i>>3, dp=i&7, d0=2*dp, d1=2*dp+1;
    float v0=(s<S&&d0<D)?Wf[s*D+d0]:0.f, v1=(s<S&&d1<D)?Wf[s*D+d1]:0.f;
    wf[i] = __floats2half2_rn(v0,v1);
  }
}

// One wave per block. 2 elems/wave: token rows 0-31 = elem A, 32-63 = elem B.
// L1 swapped: mfma(Wc1, AZ) -> lane holds H[h=mt*16+g*4+q][tok=nt*16+a]
//   -> 4 consecutive-h values pack to ONE b64 row-major write into HB[tok][h].
// AZ rows 80B, HB rows 144B (odd multiples of 16B -> <=2-way LDS banks).
#define AZS 80
#define HBS 144
__global__ __launch_bounds__(64, 2)
void solver_kernel(const float* __restrict__ x,
                   const f16x8* __restrict__ wc1, const f16x8* __restrict__ woc,
                   const f16x2* __restrict__ wf,
                   float* __restrict__ outk, float* __restrict__ d2p, float* __restrict__ f2p){
  const int l = threadIdx.x;
  const int a = l & 15;
  const int g = l >> 4;
  const int elemA = blockIdx.x*2;

  __shared__ __align__(16) unsigned char AZ[64*AZS];  // [64 tok][k f16: x|z|1|pad]
  __shared__ __align__(16) unsigned char HB[64*HBS];  // [64 tok][64 h f16]

  // prologue: zero AZ row l, stage x (k 0..13) and 1.0 (k=28)
#pragma unroll
  for (int i=0;i<20;++i) *(float*)(AZ + l*AZS + i*4) = 0.f;
  {
    int s = l & 31, e = l >> 5;
    if (s < S){
      const float* xr = x + ((size_t)(elemA+e)*S + s)*D;
#pragma unroll
      for (int i=0;i<7;++i){
        __half2 h2 = __floats2half2_rn(xr[2*i], xr[2*i+1]);
        *(f16x2*)(AZ + l*AZS + i*4) = __builtin_bit_cast(f16x2, h2);
      }
    }
    *(_Float16*)(AZ + l*AZS + 56) = (_Float16)1.0f;   // k=28 bias column
  }
  // loop-invariant fragments in registers (zero in-loop global loads)
  const f16x8 wc1f0 = wc1[( 0+a)*4 + g], wc1f1 = wc1[(16+a)*4 + g];
  const f16x8 wc1f2 = wc1[(32+a)*4 + g], wc1f3 = wc1[(48+a)*4 + g];
  const f16x8 wA0 = woc[a*8 + g], wA1 = woc[a*8 + 4 + g];
  // per-lane Wf frags: rows r=nt*16+a -> s=(nt&1)*16+a; dims g*4..g*4+3
  const f16x2 wfr0 = wf[a*8+g*2],      wfr1 = wf[a*8+g*2+1];
  const f16x2 wfr2 = wf[(16+a)*8+g*2], wfr3 = wf[(16+a)*8+g*2+1];

  const f16x2 zz = {(_Float16)0.f,(_Float16)0.f};
  const int zo0 = 28 + g*8;                      // z bytes (d-pair g*4)
  const int zo1 = (g==3) ? 60 : 32 + g*8;        // g=3 2nd pair = pad dims (k30/31, x0 weight)

  // history: [6 slots][8 = nt*2+w] f16x2 ; lane owns tokens nt*16+a, dims g*4+0..3
  f16x2 Fh[48], Gh[48], fo[8];
  float GG[21];
#pragma unroll
  for (int i=0;i<48;++i){ Fh[i]=zz; Gh[i]=zz; }
#pragma unroll
  for (int i=0;i<21;++i) GG[i]=0.f;

#pragma unroll 1
  for (int kk=0; kk<50; ++kk){
    if (kk >= 2){
      float A_[21], yv[6];
      if (kk >= 6){
#pragma unroll
        for (int i=0;i<6;++i)
#pragma unroll
          for (int j=i;j<6;++j) A_[AIJ(i,j)] = GG[AIJ(i,j)] + ((i==j)?LAMR:0.f);
      } else {
        int lo = 6-kk;
#pragma unroll
        for (int i=0;i<6;++i)
#pragma unroll
          for (int j=i;j<6;++j){
            float v = GG[AIJ(i,j)] + ((i==j)?LAMR:0.f);
            A_[AIJ(i,j)] = (i>=lo)? v : ((i==j)?1e30f:0.f);
          }
      }
#pragma unroll
      for (int i=0;i<6;++i) yv[i]=1.f;
#pragma unroll
      for (int p=0;p<6;++p){
        float ip = FRCP(A_[AIJ(p,p)]);
        A_[AIJ(p,p)] = ip;
#pragma unroll
        for (int i=p+1;i<6;++i){
          float m = A_[AIJ(p,i)]*ip;
#pragma unroll
          for (int j=i;j<6;++j) A_[AIJ(i,j)] -= m*A_[AIJ(p,j)];
          yv[i] -= m*yv[p];
        }
      }
#pragma unroll
      for (int p=5;p>=0;--p){
        float acc=yv[p];
#pragma unroll
        for (int j=p+1;j<6;++j) acc -= A_[AIJ(p,j)]*yv[j];
        yv[p]=acc*A_[AIJ(p,p)];
      }
      float isum = FRCP(yv[0]+yv[1]+yv[2]+yv[3]+yv[4]+yv[5]);
      // Xk = sum_j alpha_j F_j ; alphas per elem (half-wave solves), exchanged
      f16x2 xk[8];
#pragma unroll
      for (int i=0;i<8;++i) xk[i]=zz;
#pragma unroll
      for (int j=0;j<6;++j){
        float ao = yv[j]*isum;
        float ot = __shfl_xor(ao, 32);
        float vA = (l<32)? ao : ot;
        float vB = (l<32)? ot : ao;
        _Float16 hA=(_Float16)vA, hB=(_Float16)vB;
        f16x2 a2A={hA,hA}, a2B={hB,hB};
#pragma unroll
        for (int i=0;i<4;++i) xk[i] += a2A*Fh[j*8+i];
#pragma unroll
        for (int i=4;i<8;++i) xk[i] += a2B*Fh[j*8+i];
      }
#pragma unroll
      for (int nt=0;nt<4;++nt){
        int r = nt*16 + a;
        *(f16x2*)(AZ + r*AZS + zo0) = xk[nt*2];
        *(f16x2*)(AZ + r*AZS + zo1) = xk[nt*2+1];
      }
    } else if (kk == 1){
      // X1 = F0
#pragma unroll
      for (int nt=0;nt<4;++nt){
        int r = nt*16 + a;
        *(f16x2*)(AZ + r*AZS + zo0) = fo[nt*2];
        *(f16x2*)(AZ + r*AZS + zo1) = fo[nt*2+1];
      }
    }
    // ---- L1 (swapped): H = tanh(Wc1·[x|z|1]^T) -> HB[tok][h], b64 packed writes
#pragma unroll
    for (int nt=0;nt<4;++nt){
      f16x8 B = *(const f16x8*)(AZ + (nt*16+a)*AZS + g*16);
#pragma unroll
      for (int mt=0;mt<4;++mt){
        f32x4 c = {0.f,0.f,0.f,0.f};
        f16x8 A = (mt==0)? wc1f0 : (mt==1)? wc1f1 : (mt==2)? wc1f2 : wc1f3;
        c = __builtin_amdgcn_mfma_f32_16x16x32_f16(A, B, c, 0,0,0);
        f16x4 hv;
#pragma unroll
        for (int q=0;q<4;++q){
          _Float16 t = (_Float16)tfast(c[q]);
          if (mt==3 && g==0 && q==2) t = (_Float16)1.0f;   // h==50: bo column
          hv[q] = t;
        }
        *(f16x4*)(HB + (nt*16+a)*HBS + mt*32 + g*8) = hv;
      }
    }
    // ---- L2: F = tanh(Wo·H^T) ; lane gets F[d=g*4+q][tok=nt*16+a]
#pragma unroll
    for (int nt=0;nt<4;++nt){
      int r2 = nt*16 + a;
      f16x8 b0 = *(const f16x8*)(HB + r2*HBS +  0 + g*16);
      f16x8 b1 = *(const f16x8*)(HB + r2*HBS + 64 + g*16);
      f32x4 c = {0.f,0.f,0.f,0.f};
      c = __builtin_amdgcn_mfma_f32_16x16x32_f16(wA0, b0, c, 0,0,0);
      c = __builtin_amdgcn_mfma_f32_16x16x32_f16(wA1, b1, c, 0,0,0);
      fo[nt*2]   = pkrtz(tfast(c[0]), tfast(c[1]));
      fo[nt*2+1] = pkrtz(tfast(c[2]), tfast(c[3]));
    }
    // ---- g = F - X (X read back from AZ staging; pads zero by construction)
    f16x2 go[8];
#pragma unroll
    for (int nt=0;nt<4;++nt){
      int r = nt*16 + a;
      f16x2 x0 = *(const f16x2*)(AZ + r*AZS + zo0);
      f16x2 x1 = *(const f16x2*)(AZ + r*AZS + zo1);
      go[nt*2]   = fo[nt*2]   - x0;
      go[nt*2+1] = fo[nt*2+1] - x1;
    }
    if (a == 15){  // s==31 rows (nt odd) are inactive
      fo[2]=zz; fo[3]=zz; fo[6]=zz; fo[7]=zz;
      go[2]=zz; go[3]=zz; go[6]=zz; go[7]=zz;
    }
    // ---- push: shift FIRST, then dots from history
#pragma unroll
    for (int j=0;j<5;++j)
#pragma unroll
      for (int i=0;i<8;++i){ Fh[j*8+i]=Fh[(j+1)*8+i]; Gh[j*8+i]=Gh[(j+1)*8+i]; }
#pragma unroll
    for (int i=0;i<8;++i){ Fh[40+i]=fo[i]; Gh[40+i]=go[i]; }
    float rv[16];   // [0..7]=elem A {dn0..4,d2,f2,po}, [8..15]=elem B
#pragma unroll
    for (int j=0;j<5;++j){
      float pa=0.f, pb=0.f;
#pragma unroll
      for (int i=0;i<4;++i) pa = FDOT2(Gh[40+i], Gh[j*8+i], pa);
#pragma unroll
      for (int i=4;i<8;++i) pb = FDOT2(Gh[40+i], Gh[j*8+i], pb);
      rv[j]=pa; rv[8+j]=pb;
    }
    {
      float pa=0.f,pb=0.f,qa=0.f,qb=0.f,ra=0.f,rb=0.f;
#pragma unroll
      for (int i=0;i<4;++i){
        pa = FDOT2(Gh[40+i], Gh[40+i], pa);
        qa = FDOT2(Fh[40+i], Fh[40+i], qa);
      }
#pragma unroll
      for (int i=4;i<8;++i){
        pb = FDOT2(Gh[40+i], Gh[40+i], pb);
        qb = FDOT2(Fh[40+i], Fh[40+i], qb);
      }
      ra = FDOT2(Fh[40+0], wfr0, ra); ra = FDOT2(Fh[40+1], wfr1, ra);
      ra = FDOT2(Fh[40+2], wfr2, ra); ra = FDOT2(Fh[40+3], wfr3, ra);
      rb = FDOT2(Fh[44+0], wfr0, rb); rb = FDOT2(Fh[44+1], wfr1, rb);
      rb = FDOT2(Fh[44+2], wfr2, rb); rb = FDOT2(Fh[44+3], wfr3, rb);
      rv[5]=pa; rv[13]=pb; rv[6]=qa; rv[14]=qb; rv[7]=ra; rv[15]=rb;
    }
#pragma unroll
    for (int i=0;i<16;++i) rv[i] = dppadd<0x121>(rv[i]);
#pragma unroll
    for (int i=0;i<16;++i) rv[i] = dppadd<0x122>(rv[i]);
#pragma unroll
    for (int i=0;i<16;++i) rv[i] = dppadd<0x124>(rv[i]);
#pragma unroll
    for (int i=0;i<16;++i) rv[i] = dppadd<0x128>(rv[i]);
#pragma unroll
    for (int i=0;i<16;++i) rv[i] += __shfl_xor(rv[i],16);
#pragma unroll
    for (int i=0;i<16;++i) rv[i] += __shfl_xor(rv[i],32);
    // GG update with own-elem values (lane<32 solves A, else B)
    const bool eB = (l >= 32);
#pragma unroll
    for (int i_=0;i_<5;++i_)
#pragma unroll
      for (int j_=i_;j_<5;++j_) GG[AIJ(i_,j_)] = GG[AIJ(i_+1,j_+1)];
#pragma unroll
    for (int j=0;j<5;++j) GG[AIJ(j,5)] = eB? rv[8+j] : rv[j];
    GG[AIJ(5,5)] = eB? rv[13] : rv[5];
    if (kk>=2 && l==0){
      atomicAdd(&d2p[kk-2], rv[5]+rv[13]);
      atomicAdd(&f2p[kk-2], rv[6]+rv[14]);
      outk[(size_t)(kk-2)*NB + elemA]     = rv[7];
      outk[(size_t)(kk-2)*NB + elemA + 1] = rv[15];
    }
  }
}

__global__ void final_kernel(const float* __restrict__ d2p, const float* __restrict__ f2p,
                             const float* __restrict__ outk, const float* __restrict__ bf,
                             float* __restrict__ out){
  int b = blockIdx.x*blockDim.x + threadIdx.x;
  float best = 1e8f; int kst = 0;
  for (int k=0;k<NITER;++k){
    float rel = sqrtf(d2p[k]) / (1e-5f + sqrtf(f2p[k]));
    if (rel < best){ best = rel; kst = k; }
  }
  out[b] = outk[(size_t)kst*NB + b] + bf[0];
}

extern "C" void kernel_launch(void* const* d_in, const int* in_sizes, int n_in,
                              void* d_out, int out_size, void* d_ws, size_t ws_size,
                              hipStream_t stream){
  const float* x  = (const float*)d_in[0];
  const float* Wh = (const float*)d_in[1];
  const float* bh = (const float*)d_in[2];
  const float* Wx = (const float*)d_in[3];
  const float* bx = (const float*)d_in[4];
  const float* Wo = (const float*)d_in[5];
  const float* bo = (const float*)d_in[6];
  const float* Wf = (const float*)d_in[7];
  const float* bf = (const float*)d_in[8];
  float* ws  = (float*)d_ws;
  float* out = (float*)d_out;

  hipLaunchKernelGGL(prep_kernel, dim3(1), dim3(256), 0, stream, Wh,bh,Wx,bx,Wo,bo,Wf,ws);
  hipLaunchKernelGGL(solver_kernel, dim3(NB/2), dim3(64), 0, stream,
                     x, (const f16x8*)(ws+WS_WC1), (const f16x8*)(ws+WS_WOC),
                     (const f16x2*)(ws+WS_WF),
                     ws+WS_OUTK, ws+WS_D2, ws+WS_F2);
  hipLaunchKernelGGL(final_kernel, dim3(NB/256), dim3(256), 0, stream,
                     ws+WS_D2, ws+WS_F2, ws+WS_OUTK, bf, out);
}